// Round 18
// baseline (243.846 us; speedup 1.0000x reference)
//
#include <hip/hip_runtime.h>
#include <hip/hip_bf16.h>
#include <hip/hip_cooperative_groups.h>
#include <math.h>

namespace cg = cooperative_groups;

#define NN 50000
#define NM 10000
#define NE 400000
#define CD 256
#define C2 16

#define CDIV(a,b) (((a)+(b)-1)/(b))
#define NB_GEMM ((NN + 63) / 64)     // 782
#define NB_EDGE ((NE + 255) / 256)   // 1563
#define NB_E2 ((NE + 511) / 512)     // 782 (2 edges/thread fill blocks)
#define NBN ((NN + 1023) / 1024)     // 49
#define NBM ((NM + 1023) / 1024)     // 10

typedef __attribute__((ext_vector_type(8))) short short8v;
typedef __attribute__((ext_vector_type(8))) unsigned short ushort8v;
typedef __attribute__((ext_vector_type(4))) float f32x4;

__device__ __forceinline__ unsigned short f2bf(float f) {
    union { __hip_bfloat16 h; unsigned short u; } cv;
    cv.h = __float2bfloat16(f);
    return cv.u;
}
__device__ __forceinline__ unsigned int packbf2(float a, float b) {
    return (unsigned int)f2bf(a) | ((unsigned int)f2bf(b) << 16);
}
__device__ __forceinline__ float bf1(unsigned short u) { return __uint_as_float(((unsigned int)u) << 16); }
__device__ __forceinline__ float lrelu(float s) { return s > 0.f ? s : 0.2f * s; }

// ---------------- count (split node/hedge; saves atomic return = segment rank) + convW1 ----------------
// copy mapping = (e>>8)&7, MUST match fill's mapping
__global__ __launch_bounds__(256) void count_kernel(const int* __restrict__ node_idx,
        const int* __restrict__ hedge_idx,
        int* __restrict__ deg8n, int* __restrict__ deg8h,
        int* __restrict__ rank_n, int* __restrict__ rank_h,
        const float* __restrict__ W1, unsigned short* __restrict__ W1t) {
    int b = blockIdx.x, t = threadIdx.x;
    if (b < NB_EDGE) {
        int e = b * 256 + t;
        if (e < NE) rank_n[e] = atomicAdd(&deg8n[(b & 7) * NN + node_idx[e]], 1);
    } else if (b < 2 * NB_EDGE) {
        int chunk = b - NB_EDGE;
        int e = chunk * 256 + t;
        if (e < NE) rank_h[e] = atomicAdd(&deg8h[(chunk & 7) * NM + hedge_idx[e]], 1);
    } else {
        int col = b - 2 * NB_EDGE;
        W1t[col * 256 + t] = f2bf(W1[t * 256 + col]);
    }
}

// ---------------- merged scan (cooperative): local prefix -> grid.sync -> finalize + cnt8 ----------------
// deg8 values held in registers across the sync (single pass over deg8)
__global__ __launch_bounds__(1024) void scan_all_kernel(const int* __restrict__ deg8n,
        int* __restrict__ off_n, int* __restrict__ bsum_n,
        const int* __restrict__ deg8h, int* __restrict__ off_h, int* __restrict__ bsum_h,
        int* __restrict__ cnt8n, int* __restrict__ cnt8h) {
    cg::grid_group grid = cg::this_grid();
    __shared__ int lds[1024];
    __shared__ int base_s;
    int t = threadIdx.x, b = blockIdx.x;
    const int* deg8; int* off; int* bsum; int* cnt8; int n; int lb; int nblk;
    if (b < NBN) { deg8 = deg8n; off = off_n; bsum = bsum_n; cnt8 = cnt8n; n = NN; lb = b; nblk = NBN; }
    else { deg8 = deg8h; off = off_h; bsum = bsum_h; cnt8 = cnt8h; n = NM; lb = b - NBN; nblk = NBM; }
    int i = lb * 1024 + t;
    int d8[8] = {0, 0, 0, 0, 0, 0, 0, 0};
    int v = 0;
    if (i < n) {
        #pragma unroll
        for (int c = 0; c < 8; ++c) { d8[c] = deg8[c * n + i]; v += d8[c]; }
    }
    lds[t] = v;
    __syncthreads();
    for (int s = 1; s < 1024; s <<= 1) {
        int tv = (t >= s) ? lds[t - s] : 0;
        __syncthreads();
        lds[t] += tv;
        __syncthreads();
    }
    int local = lds[t] - v;       // exclusive prefix within block
    if (t == 1023) bsum[lb] = lds[t];
    grid.sync();
    if (t == 0) {
        int run = 0;
        for (int j = 0; j < lb; ++j) run += bsum[j];
        base_s = run;
        if (lb == 0) {
            int tot = 0;
            for (int j = 0; j < nblk; ++j) tot += bsum[j];
            off[n] = tot;
        }
    }
    __syncthreads();
    if (i < n) {
        int base = local + base_s;
        off[i] = base;
        #pragma unroll
        for (int c = 0; c < 8; ++c) { cnt8[c * n + i] = base; base += d8[c]; }
    }
}

// ---------------- fused MFMA GEMM + ATOMIC-FREE CSR fill (rank-based, 2 edges/thread) ----------------
// GEMM: xl(bf16)[R,256] = A(f32)[R,256] @ W1; fused sn+snh into sns[R,16]
__global__ __launch_bounds__(256) void gemm_fill(const float* __restrict__ A,
        const unsigned short* __restrict__ Bt, const float* __restrict__ att1,
        unsigned short* __restrict__ Cbf, float* __restrict__ sns, int R,
        const int* __restrict__ node_idx, const int* __restrict__ hedge_idx,
        const int* __restrict__ cnt8n, const int* __restrict__ cnt8h,
        const int* __restrict__ rank_n, const int* __restrict__ rank_h,
        int* __restrict__ mcol, int* __restrict__ ncol) {
    __shared__ float smem[8512];                             // 34 KB
    int t = threadIdx.x;
    if ((int)blockIdx.x >= NB_GEMM) {
        int fi = (int)blockIdx.x - NB_GEMM;
        int base = fi * 512 + t;
        #pragma unroll
        for (int j = 0; j < 2; ++j) {
            int e = base + j * 256;
            if (e < NE) {
                int cpy = (e >> 8) & 7;
                int n = node_idx[e];
                int m = hedge_idx[e];
                mcol[cnt8n[cpy * NN + n] + rank_n[e]] = m;
                ncol[cnt8h[cpy * NM + m] + rank_h[e]] = n;
            }
        }
        return;
    }
    unsigned short* As = (unsigned short*)smem;              // [64][40]
    unsigned short* Bs = (unsigned short*)(smem + 1280);     // [256][40]
    int row0 = blockIdx.x * 64;
    int lane = t & 63, wave = t >> 6;
    int wrow = (wave >> 1) * 32, wcol = (wave & 1) * 128;
    int quad = lane >> 4, l15 = lane & 15;
    f32x4 acc[2][8] = {};
    for (int k0 = 0; k0 < 256; k0 += 32) {
        #pragma unroll
        for (int p = 0; p < 2; ++p) {
            int li = t + p * 256;
            int r = li >> 3, kq = li & 7;
            float4 x4 = make_float4(0.f, 0.f, 0.f, 0.f);
            if (row0 + r < R) x4 = *(const float4*)&A[(size_t)(row0 + r) * 256 + k0 + kq * 4];
            ushort4 u;
            u.x = f2bf(x4.x); u.y = f2bf(x4.y); u.z = f2bf(x4.z); u.w = f2bf(x4.w);
            *(ushort4*)&As[r * 40 + kq * 4] = u;
        }
        #pragma unroll
        for (int p = 0; p < 4; ++p) {
            int li = t + p * 256;
            int c = li >> 2, q = li & 3;
            *(ushort8v*)&Bs[c * 40 + q * 8] = *(const ushort8v*)&Bt[(size_t)c * 256 + k0 + q * 8];
        }
        __syncthreads();
        short8v a[2], b[8];
        #pragma unroll
        for (int mi = 0; mi < 2; ++mi)
            a[mi] = *(const short8v*)&As[(wrow + mi * 16 + l15) * 40 + quad * 8];
        #pragma unroll
        for (int ni = 0; ni < 8; ++ni)
            b[ni] = *(const short8v*)&Bs[(wcol + ni * 16 + l15) * 40 + quad * 8];
        #pragma unroll
        for (int mi = 0; mi < 2; ++mi)
            #pragma unroll
            for (int ni = 0; ni < 8; ++ni)
                acc[mi][ni] = __builtin_amdgcn_mfma_f32_16x16x32_bf16(a[mi], b[ni], acc[mi][ni], 0, 0, 0);
        __syncthreads();
    }
    for (int half = 0; half < 2; ++half) {
        if ((wave & 1) == half) {
            #pragma unroll
            for (int mi = 0; mi < 2; ++mi)
                #pragma unroll
                for (int ni = 0; ni < 8; ++ni)
                    #pragma unroll
                    for (int rg = 0; rg < 4; ++rg)
                        smem[(wrow + mi * 16 + quad * 4 + rg) * 133 + ni * 16 + l15] = acc[mi][ni][rg];
        }
        __syncthreads();
        {
            int r = t & 63, hd = t >> 6;
            int hgl = half * 4 + hd;
            float psn = 0.f, psh = 0.f;
            #pragma unroll
            for (int j = 0; j < 32; ++j) {
                float cv = smem[r * 133 + hd * 32 + j];
                psn += cv * att1[hgl * 64 + j];
                psh += cv * att1[hgl * 64 + 32 + j];
            }
            if (row0 + r < R) {
                sns[(size_t)(row0 + r) * 16 + hgl] = psn;
                sns[(size_t)(row0 + r) * 16 + 8 + hgl] = psh;
            }
        }
        {
            int r2 = t >> 2, c0 = (t & 3) * 32;
            if (row0 + r2 < R) {
                unsigned int buf[16];
                #pragma unroll
                for (int j = 0; j < 16; ++j)
                    buf[j] = packbf2(smem[r2 * 133 + c0 + 2 * j], smem[r2 * 133 + c0 + 2 * j + 1]);
                size_t base = (size_t)(row0 + r2) * 256 + half * 128 + c0;
                *(ushort8v*)&Cbf[base]      = *(ushort8v*)&buf[0];
                *(ushort8v*)&Cbf[base + 8]  = *(ushort8v*)&buf[4];
                *(ushort8v*)&Cbf[base + 16] = *(ushort8v*)&buf[8];
                *(ushort8v*)&Cbf[base + 24] = *(ushort8v*)&buf[12];
            }
        }
        __syncthreads();
    }
}

// ---------------- conv1 fused per-hedge: softmax params (no max-sub) + edge_out ----------------
// phi1[m*8+h] = {sh_h, 1/sum_exp}; node side recomputes alpha = exp(lrelu(sn+sh))*inv
__global__ __launch_bounds__(256) void hedge_fused1(const unsigned short* __restrict__ xl,
        const float* __restrict__ sns,
        const int* __restrict__ ncol, const int* __restrict__ offs,
        float2* __restrict__ phi1, unsigned short* __restrict__ edge_out) {
    __shared__ int nl[1024];
    __shared__ float ssc[2048];     // [256 rows][8 heads]; later aliased as pass-B reduce
    __shared__ float red[256];
    __shared__ float redH[512];     // [64 slots][8 heads]
    __shared__ float shv8[8], inv8[8];
    int m = blockIdx.x;
    int beg = offs[m], d = offs[m + 1] - beg;
    int t = threadIdx.x;
    for (int i = t; i < d; i += 256) nl[i] = ncol[beg + i];
    __syncthreads();
    // ---- pass 0: merged sns sweep (cache sn rows; sum snh) ----
    {
        int q = t & 3, i0 = t >> 2;
        float4 hs = make_float4(0.f, 0.f, 0.f, 0.f);
        for (int i = i0; i < d; i += 64) {
            float4 v = *(const float4*)&sns[(size_t)nl[i] * 16 + q * 4];
            if (q < 2) {
                if (i < 256) *(float4*)&ssc[i * 8 + q * 4] = v;
            } else {
                hs.x += v.x; hs.y += v.y; hs.z += v.z; hs.w += v.w;
            }
        }
        if (q >= 2) *(float4*)&redH[(i0 * 8) + (q - 2) * 4] = hs;
    }
    __syncthreads();
    if (t < 256) redH[t] += redH[t + 256];
    __syncthreads();
    for (int s = 128; s >= 8; s >>= 1) {
        if (t < s) redH[t] += redH[t + s];
        __syncthreads();
    }
    if (t < 8) shv8[t] = redH[t];
    __syncthreads();
    int h = t & 7, sl = t >> 3;
    float shvh = shv8[h];
    // ---- exp-sum (scores bounded; max-subtraction dropped) ----
    float ps = 0.f;
    for (int i = sl; i < d; i += 32) {
        float sv = (i < 256) ? ssc[i * 8 + h] : sns[(size_t)nl[i] * 16 + h];
        float e = __expf(lrelu(sv + shvh));
        if (i < 256) ssc[i * 8 + h] = e;
        ps += e;
    }
    red[t] = ps; __syncthreads();
    for (int s2 = 16; s2; s2 >>= 1) { if (sl < s2) red[t] += red[t + s2 * 8]; __syncthreads(); }
    if (t < 8) {
        float ivv = 1.0f / (red[t] + 1e-16f);
        inv8[t] = ivv;
        phi1[(size_t)m * 8 + t] = make_float2(shv8[t], ivv);
    }
    __syncthreads();
    float iv = inv8[h];
    for (int i = sl; i < d && i < 256; i += 32) ssc[i * 8 + h] *= iv;
    __syncthreads();
    // ---- pass B: weighted xl gather, 64 lanes/row (8B each), 4 slots, x8 unroll ----
    int lane64 = t & 63, slot = t >> 6;
    int c4 = lane64 * 4;
    int hh = lane64 >> 3;
    float iv2 = inv8[hh], sv2 = shv8[hh];
    float acc4[4] = {};
    int i = slot;
    for (; i + 28 < d; i += 32) {
        float av[8]; ushort4 uv[8];
        #pragma unroll
        for (int r = 0; r < 8; ++r) {
            int ii = i + r * 4;
            int nr = nl[ii];
            av[r] = (ii < 256) ? ssc[ii * 8 + hh]
                  : __expf(lrelu(sns[(size_t)nr * 16 + hh] + sv2)) * iv2;
            uv[r] = *(const ushort4*)&xl[(size_t)nr * 256 + c4];
        }
        #pragma unroll
        for (int r = 0; r < 8; ++r) {
            acc4[0] += av[r] * bf1(uv[r].x);
            acc4[1] += av[r] * bf1(uv[r].y);
            acc4[2] += av[r] * bf1(uv[r].z);
            acc4[3] += av[r] * bf1(uv[r].w);
        }
    }
    for (; i < d; i += 4) {
        int nr = nl[i];
        float a = (i < 256) ? ssc[i * 8 + hh]
               : __expf(lrelu(sns[(size_t)nr * 16 + hh] + sv2)) * iv2;
        ushort4 u = *(const ushort4*)&xl[(size_t)nr * 256 + c4];
        acc4[0] += a * bf1(u.x); acc4[1] += a * bf1(u.y);
        acc4[2] += a * bf1(u.z); acc4[3] += a * bf1(u.w);
    }
    __syncthreads();
    float* redA = ssc;
    *(float4*)&redA[t * 4] = make_float4(acc4[0], acc4[1], acc4[2], acc4[3]);
    __syncthreads();
    if (slot < 2) {
        #pragma unroll
        for (int j = 0; j < 4; ++j) redA[t * 4 + j] += redA[(t + 128) * 4 + j];
    }
    __syncthreads();
    if (slot < 1) {
        #pragma unroll
        for (int j = 0; j < 4; ++j) redA[t * 4 + j] += redA[(t + 64) * 4 + j];
    }
    __syncthreads();
    if (t < 64) {
        float Bv = d ? 1.0f / (float)d : 0.0f;
        uint2 uu;
        uu.x = packbf2(redA[t * 4] * Bv, redA[t * 4 + 1] * Bv);
        uu.y = packbf2(redA[t * 4 + 2] * Bv, redA[t * 4 + 3] * Bv);
        *(uint2*)&edge_out[(size_t)m * 256 + t * 4] = uu;
    }
}

// ---------------- fused conv1-node-agg (alpha recomputed) + conv2 GEMM: 16 nodes/block ----------------
#define ALS 264
__global__ __launch_bounds__(256) void node_conv2_fused(const unsigned short* __restrict__ edge_out,
        const float2* __restrict__ phi1, const float* __restrict__ sns,
        const int* __restrict__ mcol,
        const int* __restrict__ offs, const float* __restrict__ b1,
        const float* __restrict__ W2, const float* __restrict__ att2,
        float* __restrict__ xl2, float2* __restrict__ sns2) {
    __shared__ float W2L[4096];
    __shared__ unsigned short AL[16 * ALS];
    __shared__ float b1L[256];
    int t = threadIdx.x;
    for (int i = t; i < 4096; i += 256) W2L[i] = W2[i];
    if (t < 256) b1L[t] = b1[t];
    int r = t >> 4, c = t & 15;
    int n = blockIdx.x * 16 + r;
    int beg = offs[n], end = offs[n + 1];
    int h = c >> 1;
    float sn_h = sns[(size_t)n * 16 + h];
    float acc[16] = {};
    int p = beg;
    for (; p + 3 < end; p += 4) {
        int m0 = mcol[p], m1 = mcol[p + 1], m2 = mcol[p + 2], m3 = mcol[p + 3];
        float2 f0 = phi1[(size_t)m0 * 8 + h];
        float2 f1 = phi1[(size_t)m1 * 8 + h];
        float2 f2 = phi1[(size_t)m2 * 8 + h];
        float2 f3 = phi1[(size_t)m3 * 8 + h];
        float aA = __expf(lrelu(sn_h + f0.x)) * f0.y;
        float aB = __expf(lrelu(sn_h + f1.x)) * f1.y;
        float aC = __expf(lrelu(sn_h + f2.x)) * f2.y;
        float aD = __expf(lrelu(sn_h + f3.x)) * f3.y;
        ushort8v u0a = *(const ushort8v*)&edge_out[(size_t)m0 * 256 + c * 16];
        ushort8v u0b = *(const ushort8v*)&edge_out[(size_t)m0 * 256 + c * 16 + 8];
        ushort8v u1a = *(const ushort8v*)&edge_out[(size_t)m1 * 256 + c * 16];
        ushort8v u1b = *(const ushort8v*)&edge_out[(size_t)m1 * 256 + c * 16 + 8];
        ushort8v u2a = *(const ushort8v*)&edge_out[(size_t)m2 * 256 + c * 16];
        ushort8v u2b = *(const ushort8v*)&edge_out[(size_t)m2 * 256 + c * 16 + 8];
        ushort8v u3a = *(const ushort8v*)&edge_out[(size_t)m3 * 256 + c * 16];
        ushort8v u3b = *(const ushort8v*)&edge_out[(size_t)m3 * 256 + c * 16 + 8];
        #pragma unroll
        for (int j = 0; j < 8; ++j) {
            acc[j]     += aA * bf1((unsigned short)u0a[j]) + aB * bf1((unsigned short)u1a[j])
                        + aC * bf1((unsigned short)u2a[j]) + aD * bf1((unsigned short)u3a[j]);
            acc[j + 8] += aA * bf1((unsigned short)u0b[j]) + aB * bf1((unsigned short)u1b[j])
                        + aC * bf1((unsigned short)u2b[j]) + aD * bf1((unsigned short)u3b[j]);
        }
    }
    for (; p < end; ++p) {
        int m0 = mcol[p];
        float2 f0 = phi1[(size_t)m0 * 8 + h];
        float aA = __expf(lrelu(sn_h + f0.x)) * f0.y;
        ushort8v u0a = *(const ushort8v*)&edge_out[(size_t)m0 * 256 + c * 16];
        ushort8v u0b = *(const ushort8v*)&edge_out[(size_t)m0 * 256 + c * 16 + 8];
        #pragma unroll
        for (int j = 0; j < 8; ++j) {
            acc[j]     += aA * bf1((unsigned short)u0a[j]);
            acc[j + 8] += aA * bf1((unsigned short)u0b[j]);
        }
    }
    __syncthreads();
    int dd = end - beg;
    float D = dd ? 1.0f / (float)dd : 0.0f;
    {
        unsigned short tmp[16];
        #pragma unroll
        for (int j = 0; j < 16; ++j) {
            float v = acc[j] * D + b1L[c * 16 + j];
            tmp[j] = f2bf(v > 0.f ? v : 0.f);
        }
        *(ushort8v*)&AL[r * ALS + c * 16]     = *(ushort8v*)&tmp[0];
        *(ushort8v*)&AL[r * ALS + c * 16 + 8] = *(ushort8v*)&tmp[8];
    }
    __syncthreads();
    float acc2 = 0.f;
    for (int k = 0; k < 256; k += 4) {
        ushort4 av = *(const ushort4*)&AL[r * ALS + k];
        acc2 += bf1(av.x) * W2L[k * 16 + c] + bf1(av.y) * W2L[(k + 1) * 16 + c]
              + bf1(av.z) * W2L[(k + 2) * 16 + c] + bf1(av.w) * W2L[(k + 3) * 16 + c];
    }
    float svn = acc2 * att2[c];
    float svh = acc2 * att2[16 + c];
    #pragma unroll
    for (int s = 8; s; s >>= 1) { svn += __shfl_xor(svn, s); svh += __shfl_xor(svh, s); }
    xl2[(size_t)n * 16 + c] = acc2;
    if (c == 0) sns2[n] = make_float2(svn, svh);
}

// ---------------- conv2 fused per-hedge: phi2[m] = {sh2, 1/sum_exp} + edge_out2 ----------------
__global__ __launch_bounds__(256) void hedge_fused2(const float* __restrict__ xl2,
        const float2* __restrict__ sns2,
        const int* __restrict__ ncol, const int* __restrict__ offs,
        float2* __restrict__ phi2, float* __restrict__ edge_out2) {
    __shared__ int nl[1024];
    __shared__ float ssc[1024];
    __shared__ float red[256];
    __shared__ float sh_s, inv_s;
    int m = blockIdx.x;
    int beg = offs[m], d = offs[m + 1] - beg;
    int t = threadIdx.x;
    for (int i = t; i < d; i += 256) nl[i] = ncol[beg + i];
    __syncthreads();
    float sv = 0.f;
    for (int i = t; i < d; i += 256) {
        float2 v = sns2[nl[i]];
        ssc[i] = v.x;
        sv += v.y;
    }
    red[t] = sv; __syncthreads();
    for (int s2 = 128; s2; s2 >>= 1) { if (t < s2) red[t] += red[t + s2]; __syncthreads(); }
    if (t == 0) sh_s = red[0];
    __syncthreads();
    float sh = sh_s;
    float ps = 0.f;
    for (int i = t; i < d; i += 256) {
        float e = __expf(lrelu(ssc[i] + sh));
        ssc[i] = e;
        ps += e;
    }
    red[t] = ps; __syncthreads();
    for (int s2 = 128; s2; s2 >>= 1) { if (t < s2) red[t] += red[t + s2]; __syncthreads(); }
    if (t == 0) {
        float ivv = 1.0f / (red[0] + 1e-16f);
        inv_s = ivv;
        phi2[m] = make_float2(sh, ivv);
    }
    __syncthreads();
    float inv = inv_s;
    for (int i = t; i < d; i += 256) ssc[i] *= inv;
    __syncthreads();
    int ip = t >> 4, c = t & 15;
    float acc = 0.f;
    for (int i = ip; i < d; i += 16) acc += ssc[i] * xl2[(size_t)nl[i] * 16 + c];
    red[t] = acc; __syncthreads();
    for (int s2 = 8; s2; s2 >>= 1) { if (ip < s2) red[t] += red[t + s2 * 16]; __syncthreads(); }
    if (t < 16) {
        float Bv = d ? 1.0f / (float)d : 0.0f;
        edge_out2[(size_t)m * 16 + t] = red[t] * Bv;
    }
}

// ---------------- conv2 node aggregation (alpha recomputed) + log_softmax: 16 nodes/block ----------------
__global__ __launch_bounds__(256) void node_out2b(const float* __restrict__ edge_out2,
        const float2* __restrict__ phi2, const float2* __restrict__ sns2,
        const int* __restrict__ mcol,
        const int* __restrict__ offs, const float* __restrict__ b2, float* __restrict__ out) {
    int t = threadIdx.x;
    int n = blockIdx.x * 16 + (t >> 4);
    int c = t & 15;
    int beg = offs[n], end = offs[n + 1];
    float sn2 = sns2[n].x;
    float acc = 0.f;
    int p = beg;
    for (; p + 1 < end; p += 2) {
        int m0 = mcol[p], m1 = mcol[p + 1];
        float2 f0 = phi2[m0];
        float2 f1 = phi2[m1];
        float aA = __expf(lrelu(sn2 + f0.x)) * f0.y;
        float aB = __expf(lrelu(sn2 + f1.x)) * f1.y;
        acc += aA * edge_out2[(size_t)m0 * 16 + c] + aB * edge_out2[(size_t)m1 * 16 + c];
    }
    if (p < end) {
        int m0 = mcol[p];
        float2 f0 = phi2[m0];
        acc += __expf(lrelu(sn2 + f0.x)) * f0.y * edge_out2[(size_t)m0 * 16 + c];
    }
    int dd = end - beg;
    float D = dd ? 1.0f / (float)dd : 0.0f;
    float v = acc * D + b2[c];
    float mx = v;
    #pragma unroll
    for (int s = 8; s; s >>= 1) mx = fmaxf(mx, __shfl_xor(mx, s));
    float ex = __expf(v - mx);
    float sm = ex;
    #pragma unroll
    for (int s = 8; s; s >>= 1) sm += __shfl_xor(sm, s);
    out[(size_t)n * 16 + c] = (v - mx) - logf(sm);
}

extern "C" void kernel_launch(void* const* d_in, const int* in_sizes, int n_in,
                              void* d_out, int out_size, void* d_ws, size_t ws_size,
                              hipStream_t stream) {
    const float* x        = (const float*)d_in[0];
    const int*   node_idx = (const int*)d_in[1];
    const int*   hedge_idx= (const int*)d_in[2];
    const float* W1       = (const float*)d_in[3];
    const float* att1     = (const float*)d_in[4];
    const float* b1       = (const float*)d_in[5];
    const float* W2       = (const float*)d_in[6];
    const float* att2     = (const float*)d_in[7];
    const float* b2       = (const float*)d_in[8];
    float* out = (float*)d_out;

    char* w = (char*)d_ws;
    auto carve = [&](size_t bytes) -> char* {
        char* p = w;
        w += (bytes + 255) & ~(size_t)255;
        return p;
    };
    // zero region: privatized degree histograms
    int* deg8n = (int*)carve((size_t)8 * NN * 4);
    int* deg8h = (int*)carve((size_t)8 * NM * 4);
    char* zero_end = w;
    int* cnt8n = (int*)carve((size_t)8 * NN * 4);   // slot bases (written by scan, then read-only)
    int* cnt8h = (int*)carve((size_t)8 * NM * 4);
    int* rank_n = (int*)carve((size_t)NE * 4);
    int* rank_h = (int*)carve((size_t)NE * 4);
    int* node_off  = (int*)carve((size_t)(NN + 1) * 4);
    int* hedge_off = (int*)carve((size_t)(NM + 1) * 4);
    int* bsum_n    = (int*)carve(64 * 4);
    int* bsum_h    = (int*)carve(64 * 4);
    int* mcol      = (int*)carve((size_t)NE * 4);
    int* ncol      = (int*)carve((size_t)NE * 4);
    unsigned short* W1t = (unsigned short*)carve((size_t)256 * 256 * 2);
    unsigned short* xl  = (unsigned short*)carve((size_t)NN * CD * 2);
    float* sns     = (float*)carve((size_t)NN * 16 * 4);
    float2* phi1   = (float2*)carve((size_t)NM * 8 * 8);
    unsigned short* edge_out = (unsigned short*)carve((size_t)NM * CD * 2);
    float* xl2     = (float*)carve((size_t)NN * C2 * 4);
    float2* sns2   = (float2*)carve((size_t)NN * 8);
    float2* phi2   = (float2*)carve((size_t)NM * 8);
    float* edge_out2 = (float*)carve((size_t)NM * C2 * 4);

    hipMemsetAsync(d_ws, 0, (size_t)(zero_end - (char*)d_ws), stream);

    // split privatized count (saves ranks) + convW1
    count_kernel<<<2 * NB_EDGE + 256, 256, 0, stream>>>(node_idx, hedge_idx, deg8n, deg8h,
                                                        rank_n, rank_h, W1, W1t);

    // merged cooperative scan (single pass over deg8)
    {
        void* args[] = { (void*)&deg8n, (void*)&node_off, (void*)&bsum_n,
                         (void*)&deg8h, (void*)&hedge_off, (void*)&bsum_h,
                         (void*)&cnt8n, (void*)&cnt8h };
        hipLaunchCooperativeKernel((const void*)scan_all_kernel,
                                   dim3(NBN + NBM), dim3(1024), args, 0, stream);
    }

    // ---- conv1 GEMM + atomic-free CSR fill (2 edges/thread, independent, grid-fused) ----
    gemm_fill<<<NB_GEMM + NB_E2, 256, 0, stream>>>(x, W1t, att1, xl, sns, NN,
                                                   node_idx, hedge_idx,
                                                   cnt8n, cnt8h, rank_n, rank_h, mcol, ncol);

    hedge_fused1<<<NM, 256, 0, stream>>>(xl, sns, ncol, hedge_off, phi1, edge_out);
    node_conv2_fused<<<CDIV(NN, 16), 256, 0, stream>>>(edge_out, phi1, sns, mcol, node_off,
                                                       b1, W2, att2, xl2, sns2);
    hedge_fused2<<<NM, 256, 0, stream>>>(xl2, sns2, ncol, hedge_off, phi2, edge_out2);
    node_out2b<<<CDIV(NN, 16), 256, 0, stream>>>(edge_out2, phi2, sns2, mcol, node_off, b2, out);
}

// Round 19
// 212.939 us; speedup vs baseline: 1.1451x; 1.1451x over previous
//
#include <hip/hip_runtime.h>
#include <hip/hip_bf16.h>
#include <math.h>

#define NN 50000
#define NM 10000
#define NE 400000
#define CD 256
#define C2 16

#define CDIV(a,b) (((a)+(b)-1)/(b))
#define NB_GEMM ((NN + 63) / 64)     // 782
#define NB_EDGE ((NE + 255) / 256)   // 1563
#define NB_E2 ((NE + 511) / 512)     // 782 (2 edges/thread fill blocks)
#define NBN ((NN + 1023) / 1024)     // 49
#define NBM ((NM + 1023) / 1024)     // 10

typedef __attribute__((ext_vector_type(8))) short short8v;
typedef __attribute__((ext_vector_type(8))) unsigned short ushort8v;
typedef __attribute__((ext_vector_type(4))) float f32x4;

__device__ __forceinline__ unsigned short f2bf(float f) {
    union { __hip_bfloat16 h; unsigned short u; } cv;
    cv.h = __float2bfloat16(f);
    return cv.u;
}
__device__ __forceinline__ unsigned int packbf2(float a, float b) {
    return (unsigned int)f2bf(a) | ((unsigned int)f2bf(b) << 16);
}
__device__ __forceinline__ float bf1(unsigned short u) { return __uint_as_float(((unsigned int)u) << 16); }
__device__ __forceinline__ float lrelu(float s) { return s > 0.f ? s : 0.2f * s; }

// ---------------- count (split node/hedge; saves atomic return = segment rank) + convW1 ----------------
__global__ __launch_bounds__(256) void count_kernel(const int* __restrict__ node_idx,
        const int* __restrict__ hedge_idx,
        int* __restrict__ deg8n, int* __restrict__ deg8h,
        int* __restrict__ rank_n, int* __restrict__ rank_h,
        const float* __restrict__ W1, unsigned short* __restrict__ W1t) {
    int b = blockIdx.x, t = threadIdx.x;
    if (b < NB_EDGE) {
        int e = b * 256 + t;
        if (e < NE) rank_n[e] = atomicAdd(&deg8n[(b & 7) * NN + node_idx[e]], 1);
    } else if (b < 2 * NB_EDGE) {
        int chunk = b - NB_EDGE;
        int e = chunk * 256 + t;
        if (e < NE) rank_h[e] = atomicAdd(&deg8h[(chunk & 7) * NM + hedge_idx[e]], 1);
    } else {
        int col = b - 2 * NB_EDGE;
        W1t[col * 256 + t] = f2bf(W1[t * 256 + col]);
    }
}

// ---------------- scanA: per-block local prefix + block totals ----------------
__global__ __launch_bounds__(1024) void scanA_kernel(const int* __restrict__ deg8n,
        int* __restrict__ off_n, int* __restrict__ bsum_n,
        const int* __restrict__ deg8h, int* __restrict__ off_h, int* __restrict__ bsum_h) {
    __shared__ int lds[1024];
    int t = threadIdx.x, b = blockIdx.x;
    const int* deg8; int* off; int* bsum; int n; int lb;
    if (b < NBN) { deg8 = deg8n; off = off_n; bsum = bsum_n; n = NN; lb = b; }
    else { deg8 = deg8h; off = off_h; bsum = bsum_h; n = NM; lb = b - NBN; }
    int i = lb * 1024 + t;
    int v = 0;
    if (i < n) {
        #pragma unroll
        for (int c = 0; c < 8; ++c) v += deg8[c * n + i];
    }
    lds[t] = v;
    __syncthreads();
    for (int s = 1; s < 1024; s <<= 1) {
        int tv = (t >= s) ? lds[t - s] : 0;
        __syncthreads();
        lds[t] += tv;
        __syncthreads();
    }
    if (i < n) off[i] = lds[t] - v;
    if (t == 1023) bsum[lb] = lds[t];
}

// ---------------- scanC: inline bsum prefix + finalize offsets + cnt8 bases ----------------
__global__ __launch_bounds__(1024) void scanC_kernel(int* __restrict__ off_n,
        const int* __restrict__ bsum_n, const int* __restrict__ deg8n, int* __restrict__ cnt8n,
        int* __restrict__ off_h, const int* __restrict__ bsum_h,
        const int* __restrict__ deg8h, int* __restrict__ cnt8h) {
    __shared__ int base_s;
    int b = blockIdx.x, t = threadIdx.x;
    if (b < NBN) {
        int lb = b;
        if (t == 0) {
            int run = 0;
            for (int j = 0; j < lb; ++j) run += bsum_n[j];
            base_s = run;
            if (lb == 0) {
                int tot = 0;
                for (int j = 0; j < NBN; ++j) tot += bsum_n[j];
                off_n[NN] = tot;
            }
        }
        __syncthreads();
        int blockbase = base_s;
        int i = lb * 1024 + t;
        if (i < NN) {
            int base = off_n[i] + blockbase;
            off_n[i] = base;
            #pragma unroll
            for (int c = 0; c < 8; ++c) { cnt8n[c * NN + i] = base; base += deg8n[c * NN + i]; }
        }
    } else {
        int lb = b - NBN;
        if (t == 0) {
            int run = 0;
            for (int j = 0; j < lb; ++j) run += bsum_h[j];
            base_s = run;
            if (lb == 0) {
                int tot = 0;
                for (int j = 0; j < NBM; ++j) tot += bsum_h[j];
                off_h[NM] = tot;
            }
        }
        __syncthreads();
        int blockbase = base_s;
        int i = lb * 1024 + t;
        if (i < NM) {
            int base = off_h[i] + blockbase;
            off_h[i] = base;
            #pragma unroll
            for (int c = 0; c < 8; ++c) { cnt8h[c * NM + i] = base; base += deg8h[c * NM + i]; }
        }
    }
}

// ---------------- fused MFMA GEMM + ATOMIC-FREE CSR fill (rank-based, 2 edges/thread) ----------------
__global__ __launch_bounds__(256) void gemm_fill(const float* __restrict__ A,
        const unsigned short* __restrict__ Bt, const float* __restrict__ att1,
        unsigned short* __restrict__ Cbf, float* __restrict__ sns, int R,
        const int* __restrict__ node_idx, const int* __restrict__ hedge_idx,
        const int* __restrict__ cnt8n, const int* __restrict__ cnt8h,
        const int* __restrict__ rank_n, const int* __restrict__ rank_h,
        int* __restrict__ mcol, int* __restrict__ ncol) {
    __shared__ float smem[8512];                             // 34 KB
    int t = threadIdx.x;
    if ((int)blockIdx.x >= NB_GEMM) {
        int fi = (int)blockIdx.x - NB_GEMM;
        int base = fi * 512 + t;
        #pragma unroll
        for (int j = 0; j < 2; ++j) {
            int e = base + j * 256;
            if (e < NE) {
                int cpy = (e >> 8) & 7;
                int n = node_idx[e];
                int m = hedge_idx[e];
                mcol[cnt8n[cpy * NN + n] + rank_n[e]] = m;
                ncol[cnt8h[cpy * NM + m] + rank_h[e]] = n;
            }
        }
        return;
    }
    unsigned short* As = (unsigned short*)smem;              // [64][40]
    unsigned short* Bs = (unsigned short*)(smem + 1280);     // [256][40]
    int row0 = blockIdx.x * 64;
    int lane = t & 63, wave = t >> 6;
    int wrow = (wave >> 1) * 32, wcol = (wave & 1) * 128;
    int quad = lane >> 4, l15 = lane & 15;
    f32x4 acc[2][8] = {};
    for (int k0 = 0; k0 < 256; k0 += 32) {
        #pragma unroll
        for (int p = 0; p < 2; ++p) {
            int li = t + p * 256;
            int r = li >> 3, kq = li & 7;
            float4 x4 = make_float4(0.f, 0.f, 0.f, 0.f);
            if (row0 + r < R) x4 = *(const float4*)&A[(size_t)(row0 + r) * 256 + k0 + kq * 4];
            ushort4 u;
            u.x = f2bf(x4.x); u.y = f2bf(x4.y); u.z = f2bf(x4.z); u.w = f2bf(x4.w);
            *(ushort4*)&As[r * 40 + kq * 4] = u;
        }
        #pragma unroll
        for (int p = 0; p < 4; ++p) {
            int li = t + p * 256;
            int c = li >> 2, q = li & 3;
            *(ushort8v*)&Bs[c * 40 + q * 8] = *(const ushort8v*)&Bt[(size_t)c * 256 + k0 + q * 8];
        }
        __syncthreads();
        short8v a[2], b[8];
        #pragma unroll
        for (int mi = 0; mi < 2; ++mi)
            a[mi] = *(const short8v*)&As[(wrow + mi * 16 + l15) * 40 + quad * 8];
        #pragma unroll
        for (int ni = 0; ni < 8; ++ni)
            b[ni] = *(const short8v*)&Bs[(wcol + ni * 16 + l15) * 40 + quad * 8];
        #pragma unroll
        for (int mi = 0; mi < 2; ++mi)
            #pragma unroll
            for (int ni = 0; ni < 8; ++ni)
                acc[mi][ni] = __builtin_amdgcn_mfma_f32_16x16x32_bf16(a[mi], b[ni], acc[mi][ni], 0, 0, 0);
        __syncthreads();
    }
    for (int half = 0; half < 2; ++half) {
        if ((wave & 1) == half) {
            #pragma unroll
            for (int mi = 0; mi < 2; ++mi)
                #pragma unroll
                for (int ni = 0; ni < 8; ++ni)
                    #pragma unroll
                    for (int rg = 0; rg < 4; ++rg)
                        smem[(wrow + mi * 16 + quad * 4 + rg) * 133 + ni * 16 + l15] = acc[mi][ni][rg];
        }
        __syncthreads();
        {
            int r = t & 63, hd = t >> 6;
            int hgl = half * 4 + hd;
            float psn = 0.f, psh = 0.f;
            #pragma unroll
            for (int j = 0; j < 32; ++j) {
                float cv = smem[r * 133 + hd * 32 + j];
                psn += cv * att1[hgl * 64 + j];
                psh += cv * att1[hgl * 64 + 32 + j];
            }
            if (row0 + r < R) {
                sns[(size_t)(row0 + r) * 16 + hgl] = psn;
                sns[(size_t)(row0 + r) * 16 + 8 + hgl] = psh;
            }
        }
        {
            int r2 = t >> 2, c0 = (t & 3) * 32;
            if (row0 + r2 < R) {
                unsigned int buf[16];
                #pragma unroll
                for (int j = 0; j < 16; ++j)
                    buf[j] = packbf2(smem[r2 * 133 + c0 + 2 * j], smem[r2 * 133 + c0 + 2 * j + 1]);
                size_t base = (size_t)(row0 + r2) * 256 + half * 128 + c0;
                *(ushort8v*)&Cbf[base]      = *(ushort8v*)&buf[0];
                *(ushort8v*)&Cbf[base + 8]  = *(ushort8v*)&buf[4];
                *(ushort8v*)&Cbf[base + 16] = *(ushort8v*)&buf[8];
                *(ushort8v*)&Cbf[base + 24] = *(ushort8v*)&buf[12];
            }
        }
        __syncthreads();
    }
}

// ---------------- conv1 fused per-hedge: softmax params (no max-sub) + edge_out ----------------
__global__ __launch_bounds__(256) void hedge_fused1(const unsigned short* __restrict__ xl,
        const float* __restrict__ sns,
        const int* __restrict__ ncol, const int* __restrict__ offs,
        float2* __restrict__ phi1, unsigned short* __restrict__ edge_out) {
    __shared__ int nl[1024];
    __shared__ float ssc[2048];     // [256 rows][8 heads]; later aliased as pass-B reduce
    __shared__ float red[256];
    __shared__ float redH[512];     // [64 slots][8 heads]
    __shared__ float shv8[8], inv8[8];
    int m = blockIdx.x;
    int beg = offs[m], d = offs[m + 1] - beg;
    int t = threadIdx.x;
    for (int i = t; i < d; i += 256) nl[i] = ncol[beg + i];
    __syncthreads();
    // ---- pass 0: merged sns sweep (cache sn rows; sum snh) ----
    {
        int q = t & 3, i0 = t >> 2;
        float4 hs = make_float4(0.f, 0.f, 0.f, 0.f);
        for (int i = i0; i < d; i += 64) {
            float4 v = *(const float4*)&sns[(size_t)nl[i] * 16 + q * 4];
            if (q < 2) {
                if (i < 256) *(float4*)&ssc[i * 8 + q * 4] = v;
            } else {
                hs.x += v.x; hs.y += v.y; hs.z += v.z; hs.w += v.w;
            }
        }
        if (q >= 2) *(float4*)&redH[(i0 * 8) + (q - 2) * 4] = hs;
    }
    __syncthreads();
    if (t < 256) redH[t] += redH[t + 256];
    __syncthreads();
    for (int s = 128; s >= 8; s >>= 1) {
        if (t < s) redH[t] += redH[t + s];
        __syncthreads();
    }
    if (t < 8) shv8[t] = redH[t];
    __syncthreads();
    int h = t & 7, sl = t >> 3;
    float shvh = shv8[h];
    // ---- exp-sum (scores bounded; max-subtraction dropped) ----
    float ps = 0.f;
    for (int i = sl; i < d; i += 32) {
        float sv = (i < 256) ? ssc[i * 8 + h] : sns[(size_t)nl[i] * 16 + h];
        float e = __expf(lrelu(sv + shvh));
        if (i < 256) ssc[i * 8 + h] = e;
        ps += e;
    }
    red[t] = ps; __syncthreads();
    for (int s2 = 16; s2; s2 >>= 1) { if (sl < s2) red[t] += red[t + s2 * 8]; __syncthreads(); }
    if (t < 8) {
        float ivv = 1.0f / (red[t] + 1e-16f);
        inv8[t] = ivv;
        phi1[(size_t)m * 8 + t] = make_float2(shv8[t], ivv);
    }
    __syncthreads();
    float iv = inv8[h];
    for (int i = sl; i < d && i < 256; i += 32) ssc[i * 8 + h] *= iv;
    __syncthreads();
    // ---- pass B: weighted xl gather, 64 lanes/row (8B each), 4 slots, x8 unroll ----
    int lane64 = t & 63, slot = t >> 6;
    int c4 = lane64 * 4;
    int hh = lane64 >> 3;
    float iv2 = inv8[hh], sv2 = shv8[hh];
    float acc4[4] = {};
    int i = slot;
    for (; i + 28 < d; i += 32) {
        float av[8]; ushort4 uv[8];
        #pragma unroll
        for (int r = 0; r < 8; ++r) {
            int ii = i + r * 4;
            int nr = nl[ii];
            av[r] = (ii < 256) ? ssc[ii * 8 + hh]
                  : __expf(lrelu(sns[(size_t)nr * 16 + hh] + sv2)) * iv2;
            uv[r] = *(const ushort4*)&xl[(size_t)nr * 256 + c4];
        }
        #pragma unroll
        for (int r = 0; r < 8; ++r) {
            acc4[0] += av[r] * bf1(uv[r].x);
            acc4[1] += av[r] * bf1(uv[r].y);
            acc4[2] += av[r] * bf1(uv[r].z);
            acc4[3] += av[r] * bf1(uv[r].w);
        }
    }
    for (; i < d; i += 4) {
        int nr = nl[i];
        float a = (i < 256) ? ssc[i * 8 + hh]
               : __expf(lrelu(sns[(size_t)nr * 16 + hh] + sv2)) * iv2;
        ushort4 u = *(const ushort4*)&xl[(size_t)nr * 256 + c4];
        acc4[0] += a * bf1(u.x); acc4[1] += a * bf1(u.y);
        acc4[2] += a * bf1(u.z); acc4[3] += a * bf1(u.w);
    }
    __syncthreads();
    float* redA = ssc;
    *(float4*)&redA[t * 4] = make_float4(acc4[0], acc4[1], acc4[2], acc4[3]);
    __syncthreads();
    if (slot < 2) {
        #pragma unroll
        for (int j = 0; j < 4; ++j) redA[t * 4 + j] += redA[(t + 128) * 4 + j];
    }
    __syncthreads();
    if (slot < 1) {
        #pragma unroll
        for (int j = 0; j < 4; ++j) redA[t * 4 + j] += redA[(t + 64) * 4 + j];
    }
    __syncthreads();
    if (t < 64) {
        float Bv = d ? 1.0f / (float)d : 0.0f;
        uint2 uu;
        uu.x = packbf2(redA[t * 4] * Bv, redA[t * 4 + 1] * Bv);
        uu.y = packbf2(redA[t * 4 + 2] * Bv, redA[t * 4 + 3] * Bv);
        *(uint2*)&edge_out[(size_t)m * 256 + t * 4] = uu;
    }
}

// ---------------- fused conv1-node-agg (alpha recomputed) + conv2 GEMM: 16 nodes/block ----------------
#define ALS 264
__global__ __launch_bounds__(256) void node_conv2_fused(const unsigned short* __restrict__ edge_out,
        const float2* __restrict__ phi1, const float* __restrict__ sns,
        const int* __restrict__ mcol,
        const int* __restrict__ offs, const float* __restrict__ b1,
        const float* __restrict__ W2, const float* __restrict__ att2,
        float* __restrict__ xl2, float2* __restrict__ sns2) {
    __shared__ float W2L[4096];
    __shared__ unsigned short AL[16 * ALS];
    __shared__ float b1L[256];
    int t = threadIdx.x;
    for (int i = t; i < 4096; i += 256) W2L[i] = W2[i];
    if (t < 256) b1L[t] = b1[t];
    int r = t >> 4, c = t & 15;
    int n = blockIdx.x * 16 + r;
    int beg = offs[n], end = offs[n + 1];
    int h = c >> 1;
    float sn_h = sns[(size_t)n * 16 + h];
    float acc[16] = {};
    int p = beg;
    for (; p + 3 < end; p += 4) {
        int m0 = mcol[p], m1 = mcol[p + 1], m2 = mcol[p + 2], m3 = mcol[p + 3];
        float2 f0 = phi1[(size_t)m0 * 8 + h];
        float2 f1 = phi1[(size_t)m1 * 8 + h];
        float2 f2 = phi1[(size_t)m2 * 8 + h];
        float2 f3 = phi1[(size_t)m3 * 8 + h];
        float aA = __expf(lrelu(sn_h + f0.x)) * f0.y;
        float aB = __expf(lrelu(sn_h + f1.x)) * f1.y;
        float aC = __expf(lrelu(sn_h + f2.x)) * f2.y;
        float aD = __expf(lrelu(sn_h + f3.x)) * f3.y;
        ushort8v u0a = *(const ushort8v*)&edge_out[(size_t)m0 * 256 + c * 16];
        ushort8v u0b = *(const ushort8v*)&edge_out[(size_t)m0 * 256 + c * 16 + 8];
        ushort8v u1a = *(const ushort8v*)&edge_out[(size_t)m1 * 256 + c * 16];
        ushort8v u1b = *(const ushort8v*)&edge_out[(size_t)m1 * 256 + c * 16 + 8];
        ushort8v u2a = *(const ushort8v*)&edge_out[(size_t)m2 * 256 + c * 16];
        ushort8v u2b = *(const ushort8v*)&edge_out[(size_t)m2 * 256 + c * 16 + 8];
        ushort8v u3a = *(const ushort8v*)&edge_out[(size_t)m3 * 256 + c * 16];
        ushort8v u3b = *(const ushort8v*)&edge_out[(size_t)m3 * 256 + c * 16 + 8];
        #pragma unroll
        for (int j = 0; j < 8; ++j) {
            acc[j]     += aA * bf1((unsigned short)u0a[j]) + aB * bf1((unsigned short)u1a[j])
                        + aC * bf1((unsigned short)u2a[j]) + aD * bf1((unsigned short)u3a[j]);
            acc[j + 8] += aA * bf1((unsigned short)u0b[j]) + aB * bf1((unsigned short)u1b[j])
                        + aC * bf1((unsigned short)u2b[j]) + aD * bf1((unsigned short)u3b[j]);
        }
    }
    for (; p < end; ++p) {
        int m0 = mcol[p];
        float2 f0 = phi1[(size_t)m0 * 8 + h];
        float aA = __expf(lrelu(sn_h + f0.x)) * f0.y;
        ushort8v u0a = *(const ushort8v*)&edge_out[(size_t)m0 * 256 + c * 16];
        ushort8v u0b = *(const ushort8v*)&edge_out[(size_t)m0 * 256 + c * 16 + 8];
        #pragma unroll
        for (int j = 0; j < 8; ++j) {
            acc[j]     += aA * bf1((unsigned short)u0a[j]);
            acc[j + 8] += aA * bf1((unsigned short)u0b[j]);
        }
    }
    __syncthreads();
    int dd = end - beg;
    float D = dd ? 1.0f / (float)dd : 0.0f;
    {
        unsigned short tmp[16];
        #pragma unroll
        for (int j = 0; j < 16; ++j) {
            float v = acc[j] * D + b1L[c * 16 + j];
            tmp[j] = f2bf(v > 0.f ? v : 0.f);
        }
        *(ushort8v*)&AL[r * ALS + c * 16]     = *(ushort8v*)&tmp[0];
        *(ushort8v*)&AL[r * ALS + c * 16 + 8] = *(ushort8v*)&tmp[8];
    }
    __syncthreads();
    float acc2 = 0.f;
    for (int k = 0; k < 256; k += 4) {
        ushort4 av = *(const ushort4*)&AL[r * ALS + k];
        acc2 += bf1(av.x) * W2L[k * 16 + c] + bf1(av.y) * W2L[(k + 1) * 16 + c]
              + bf1(av.z) * W2L[(k + 2) * 16 + c] + bf1(av.w) * W2L[(k + 3) * 16 + c];
    }
    float svn = acc2 * att2[c];
    float svh = acc2 * att2[16 + c];
    #pragma unroll
    for (int s = 8; s; s >>= 1) { svn += __shfl_xor(svn, s); svh += __shfl_xor(svh, s); }
    xl2[(size_t)n * 16 + c] = acc2;
    if (c == 0) sns2[n] = make_float2(svn, svh);
}

// ---------------- conv2 fused per-hedge: phi2[m] = {sh2, 1/sum_exp} + edge_out2 ----------------
__global__ __launch_bounds__(256) void hedge_fused2(const float* __restrict__ xl2,
        const float2* __restrict__ sns2,
        const int* __restrict__ ncol, const int* __restrict__ offs,
        float2* __restrict__ phi2, float* __restrict__ edge_out2) {
    __shared__ int nl[1024];
    __shared__ float ssc[1024];
    __shared__ float red[256];
    __shared__ float sh_s, inv_s;
    int m = blockIdx.x;
    int beg = offs[m], d = offs[m + 1] - beg;
    int t = threadIdx.x;
    for (int i = t; i < d; i += 256) nl[i] = ncol[beg + i];
    __syncthreads();
    float sv = 0.f;
    for (int i = t; i < d; i += 256) {
        float2 v = sns2[nl[i]];
        ssc[i] = v.x;
        sv += v.y;
    }
    red[t] = sv; __syncthreads();
    for (int s2 = 128; s2; s2 >>= 1) { if (t < s2) red[t] += red[t + s2]; __syncthreads(); }
    if (t == 0) sh_s = red[0];
    __syncthreads();
    float sh = sh_s;
    float ps = 0.f;
    for (int i = t; i < d; i += 256) {
        float e = __expf(lrelu(ssc[i] + sh));
        ssc[i] = e;
        ps += e;
    }
    red[t] = ps; __syncthreads();
    for (int s2 = 128; s2; s2 >>= 1) { if (t < s2) red[t] += red[t + s2]; __syncthreads(); }
    if (t == 0) {
        float ivv = 1.0f / (red[0] + 1e-16f);
        inv_s = ivv;
        phi2[m] = make_float2(sh, ivv);
    }
    __syncthreads();
    float inv = inv_s;
    for (int i = t; i < d; i += 256) ssc[i] *= inv;
    __syncthreads();
    int ip = t >> 4, c = t & 15;
    float acc = 0.f;
    for (int i = ip; i < d; i += 16) acc += ssc[i] * xl2[(size_t)nl[i] * 16 + c];
    red[t] = acc; __syncthreads();
    for (int s2 = 8; s2; s2 >>= 1) { if (ip < s2) red[t] += red[t + s2 * 16]; __syncthreads(); }
    if (t < 16) {
        float Bv = d ? 1.0f / (float)d : 0.0f;
        edge_out2[(size_t)m * 16 + t] = red[t] * Bv;
    }
}

// ---------------- conv2 node aggregation (alpha recomputed) + log_softmax: 16 nodes/block ----------------
__global__ __launch_bounds__(256) void node_out2b(const float* __restrict__ edge_out2,
        const float2* __restrict__ phi2, const float2* __restrict__ sns2,
        const int* __restrict__ mcol,
        const int* __restrict__ offs, const float* __restrict__ b2, float* __restrict__ out) {
    int t = threadIdx.x;
    int n = blockIdx.x * 16 + (t >> 4);
    int c = t & 15;
    int beg = offs[n], end = offs[n + 1];
    float sn2 = sns2[n].x;
    float acc = 0.f;
    int p = beg;
    for (; p + 1 < end; p += 2) {
        int m0 = mcol[p], m1 = mcol[p + 1];
        float2 f0 = phi2[m0];
        float2 f1 = phi2[m1];
        float aA = __expf(lrelu(sn2 + f0.x)) * f0.y;
        float aB = __expf(lrelu(sn2 + f1.x)) * f1.y;
        acc += aA * edge_out2[(size_t)m0 * 16 + c] + aB * edge_out2[(size_t)m1 * 16 + c];
    }
    if (p < end) {
        int m0 = mcol[p];
        float2 f0 = phi2[m0];
        acc += __expf(lrelu(sn2 + f0.x)) * f0.y * edge_out2[(size_t)m0 * 16 + c];
    }
    int dd = end - beg;
    float D = dd ? 1.0f / (float)dd : 0.0f;
    float v = acc * D + b2[c];
    float mx = v;
    #pragma unroll
    for (int s = 8; s; s >>= 1) mx = fmaxf(mx, __shfl_xor(mx, s));
    float ex = __expf(v - mx);
    float sm = ex;
    #pragma unroll
    for (int s = 8; s; s >>= 1) sm += __shfl_xor(sm, s);
    out[(size_t)n * 16 + c] = (v - mx) - logf(sm);
}

extern "C" void kernel_launch(void* const* d_in, const int* in_sizes, int n_in,
                              void* d_out, int out_size, void* d_ws, size_t ws_size,
                              hipStream_t stream) {
    const float* x        = (const float*)d_in[0];
    const int*   node_idx = (const int*)d_in[1];
    const int*   hedge_idx= (const int*)d_in[2];
    const float* W1       = (const float*)d_in[3];
    const float* att1     = (const float*)d_in[4];
    const float* b1       = (const float*)d_in[5];
    const float* W2       = (const float*)d_in[6];
    const float* att2     = (const float*)d_in[7];
    const float* b2       = (const float*)d_in[8];
    float* out = (float*)d_out;

    char* w = (char*)d_ws;
    auto carve = [&](size_t bytes) -> char* {
        char* p = w;
        w += (bytes + 255) & ~(size_t)255;
        return p;
    };
    // zero region: privatized degree histograms
    int* deg8n = (int*)carve((size_t)8 * NN * 4);
    int* deg8h = (int*)carve((size_t)8 * NM * 4);
    char* zero_end = w;
    int* cnt8n = (int*)carve((size_t)8 * NN * 4);   // slot bases (written by scanC, then read-only)
    int* cnt8h = (int*)carve((size_t)8 * NM * 4);
    int* rank_n = (int*)carve((size_t)NE * 4);
    int* rank_h = (int*)carve((size_t)NE * 4);
    int* node_off  = (int*)carve((size_t)(NN + 1) * 4);
    int* hedge_off = (int*)carve((size_t)(NM + 1) * 4);
    int* bsum_n    = (int*)carve(64 * 4);
    int* bsum_h    = (int*)carve(64 * 4);
    int* mcol      = (int*)carve((size_t)NE * 4);
    int* ncol      = (int*)carve((size_t)NE * 4);
    unsigned short* W1t = (unsigned short*)carve((size_t)256 * 256 * 2);
    unsigned short* xl  = (unsigned short*)carve((size_t)NN * CD * 2);
    float* sns     = (float*)carve((size_t)NN * 16 * 4);
    float2* phi1   = (float2*)carve((size_t)NM * 8 * 8);
    unsigned short* edge_out = (unsigned short*)carve((size_t)NM * CD * 2);
    float* xl2     = (float*)carve((size_t)NN * C2 * 4);
    float2* sns2   = (float2*)carve((size_t)NN * 8);
    float2* phi2   = (float2*)carve((size_t)NM * 8);
    float* edge_out2 = (float*)carve((size_t)NM * C2 * 4);

    hipMemsetAsync(d_ws, 0, (size_t)(zero_end - (char*)d_ws), stream);

    // split privatized count (saves ranks) + convW1
    count_kernel<<<2 * NB_EDGE + 256, 256, 0, stream>>>(node_idx, hedge_idx, deg8n, deg8h,
                                                        rank_n, rank_h, W1, W1t);

    scanA_kernel<<<NBN + NBM, 1024, 0, stream>>>(deg8n, node_off, bsum_n,
                                                 deg8h, hedge_off, bsum_h);
    scanC_kernel<<<NBN + NBM, 1024, 0, stream>>>(node_off, bsum_n, deg8n, cnt8n,
                                                 hedge_off, bsum_h, deg8h, cnt8h);

    // ---- conv1 GEMM + atomic-free CSR fill (2 edges/thread, independent, grid-fused) ----
    gemm_fill<<<NB_GEMM + NB_E2, 256, 0, stream>>>(x, W1t, att1, xl, sns, NN,
                                                   node_idx, hedge_idx,
                                                   cnt8n, cnt8h, rank_n, rank_h, mcol, ncol);

    hedge_fused1<<<NM, 256, 0, stream>>>(xl, sns, ncol, hedge_off, phi1, edge_out);
    node_conv2_fused<<<CDIV(NN, 16), 256, 0, stream>>>(edge_out, phi1, sns, mcol, node_off,
                                                       b1, W2, att2, xl2, sns2);
    hedge_fused2<<<NM, 256, 0, stream>>>(xl2, sns2, ncol, hedge_off, phi2, edge_out2);
    node_out2b<<<CDIV(NN, 16), 256, 0, stream>>>(edge_out2, phi2, sns2, mcol, node_off, b2, out);
}